// Round 3
// baseline (246.294 us; speedup 1.0000x reference)
//
#include <hip/hip_runtime.h>

// B=16, L=2048, K=24, D=64
typedef _Float16 f16;
typedef _Float16 f16x4 __attribute__((ext_vector_type(4)));
typedef _Float16 f16x8 __attribute__((ext_vector_type(8)));
typedef float f32x4 __attribute__((ext_vector_type(4)));

__device__ __forceinline__ void gl_lds16(const void* g, void* l) {
  __builtin_amdgcn_global_load_lds(
      (__attribute__((address_space(1))) unsigned int*)(g),
      (__attribute__((address_space(3))) unsigned int*)(l), 16, 0, 0);
}

// ---- k_pre0: ALL independent precompute arms in launch #1 (728 blocks).
//   blk 0..255:   uin conversion (pre-swizzled f16 planes for k_w)
//   blk 256..279: phiT[k][e][d] = (f16) m_phi[(k*64+d)*64+e]
//   blk 280..663: Dpre phase-replicated Toeplitz tables
//   blk 664..727: zero out[]
__global__ __launch_bounds__(256) void k_pre0(const float* __restrict__ in,
                                              const float* __restrict__ m_phi,
                                              const float* __restrict__ ev,
                                              const float* __restrict__ evec,
                                              f16* __restrict__ phiT,
                                              f16* __restrict__ uin,
                                              f16* __restrict__ Dpre,
                                              float* __restrict__ out) {
  __shared__ float esm[256];
  int blk = blockIdx.x;
  int tid = threadIdx.x;
  if (blk < 256) {  // ---- uin conversion (one 128-s x 64-d plane per block)
    int b = blk >> 4, s0 = (blk & 15) * 128;
    f16* up = uin + (size_t)blk * 8192;
#pragma unroll
    for (int v = 0; v < 4; ++v) {
      int flat = v * 256 + tid;
      int row = flat >> 3, cl = flat & 7, cg = cl ^ (row & 7);
      const float* g = in + ((size_t)(b * 2048 + s0 + row)) * 64 + cg * 8;
      float4 u0 = *(const float4*)g;
      float4 u1 = *(const float4*)(g + 4);
      f16x8 h;
      h[0] = (f16)u0.x; h[1] = (f16)u0.y; h[2] = (f16)u0.z; h[3] = (f16)u0.w;
      h[4] = (f16)u1.x; h[5] = (f16)u1.y; h[6] = (f16)u1.z; h[7] = (f16)u1.w;
      *(f16x8*)&up[flat * 8] = h;
    }
    return;
  }
  if (blk < 280) {  // ---- phiT transpose
    int k = blk - 256;
    for (int idx = tid; idx < 4096; idx += 256) {
      int e = idx >> 6, d = idx & 63;
      phiT[k * 4096 + idx] = (f16)m_phi[(k * 64 + d) * 64 + e];
    }
    return;
  }
  if (blk < 664) {  // ---- Dpre blocks (384): D[p][y]=esm[254-p-y], pad 2560
    int a = blk - 280;
    int diag = a / 24, k = a % 24;
    float s4 = sqrtf(sqrtf(ev[k]));
    int base = diag * 128 - 127;
    if (tid < 255) {
      int v = base + tid;
      esm[tid] = (v >= 0) ? evec[v * 24 + k] * s4 : 0.0f;
    }
    __syncthreads();
    f16* plane = Dpre + (size_t)(diag * 24 + k) * 2560;
    for (int i = tid; i < 2560; i += 256) {
      float val = 0.f;
      if (i < 2112) {
        int p = i / 264, y = i - p * 264;
        int g = 254 - p - y;
        if (g >= 0) val = esm[g];
      }
      plane[i] = (f16)val;
    }
    return;
  }
  // ---- zero-out blocks: 64 blocks x 32768 floats
  float4* o = (float4*)(out + (size_t)(blk - 664) * 32768);
  float4 z4 = {0.f, 0.f, 0.f, 0.f};
#pragma unroll
  for (int i = 0; i < 32; ++i) o[i * 256 + tid] = z4;
}

// ---- k_w: W3[bp][k][st][cc][row] = sum_d in[b][s][d] * m_phi[k*64+d][e]
// (quarter-chunk-major layout: chunk-col cc = j*4+c covers s = st*128+cc*8,
//  row = (b&1)*64 + e. One chunk-col = 128 rows x 8 f16 = 1024 f16.)
// k_main stages a 32-wide quarter (cc = 4j..4j+3) as 8 KB CONTIGUOUS.
__global__ __launch_bounds__(256) void k_w(const f16* __restrict__ uin,
                                           const f16* __restrict__ phiT,
                                           f16* __restrict__ W3) {
  __shared__ __align__(16) f16 Ubuf[8320];
  __shared__ __align__(16) f16 Psm[64 * 64];
  int wblk = blockIdx.x;
  int st = wblk & 15;
  int b = (wblk >> 4) & 15;
  int kg = wblk >> 8;  // 0..5
  int tid = threadIdx.x, lane = tid & 63, wv = tid >> 6;
  const f16* up = uin + (size_t)(wblk & 255) * 8192;
  // U stage: contiguous gl_lds (uin pre-swizzled by k_pre0)
#pragma unroll
  for (int v = 0; v < 4; ++v)
    gl_lds16(up + (size_t)(v * 256 + tid) * 8, &Ubuf[(v * 256 + wv * 64) * 8]);
  // P(k0) stage in the same vmcnt group
  {
    int k0 = kg * 4;
#pragma unroll
    for (int v = 0; v < 2; ++v) {
      int flat = v * 256 + tid;
      int row = flat >> 3, cl = flat & 7, cg = cl ^ (row & 7);
      gl_lds16(phiT + (size_t)k0 * 4096 + row * 64 + cg * 8,
               &Psm[(v * 256 + wv * 64) * 8]);
    }
  }
  __syncthreads();  // U + P0 resident
  int wm = wv * 32;
  f16x8 af[2][2];
#pragma unroll
  for (int ks = 0; ks < 2; ++ks)
#pragma unroll
    for (int x = 0; x < 2; ++x) {
      int m = wm + x * 16 + (lane & 15);
      int ch = (ks * 4 + (lane >> 4)) ^ (m & 7);
      af[ks][x] = *(const f16x8*)&Ubuf[m * 64 + ch * 8];
    }
  for (int ki = 0; ki < 4; ++ki) {
    int k = kg * 4 + ki;
    f32x4 zero = {0.f, 0.f, 0.f, 0.f};
    f32x4 acc[2][4];
#pragma unroll
    for (int x = 0; x < 2; ++x)
#pragma unroll
      for (int y = 0; y < 4; ++y) acc[x][y] = zero;
#pragma unroll
    for (int ks = 0; ks < 2; ++ks) {
      f16x8 bf[4];
#pragma unroll
      for (int y = 0; y < 4; ++y) {
        int n = y * 16 + (lane & 15);
        int ch = (ks * 4 + (lane >> 4)) ^ (n & 7);
        bf[y] = *(const f16x8*)&Psm[n * 64 + ch * 8];
      }
#pragma unroll
      for (int x = 0; x < 2; ++x)
#pragma unroll
        for (int y = 0; y < 4; ++y)
          acc[x][y] = __builtin_amdgcn_mfma_f32_16x16x32_f16(af[ks][x], bf[y], acc[x][y], 0, 0, 0);
    }
    __syncthreads();  // Psm reads + (iter0) af Ubuf reads done everywhere
    // transpose C (128 sigma x 64 e) into Ubuf as Csm[e][sigma], stride 130
#pragma unroll
    for (int x = 0; x < 2; ++x)
#pragma unroll
      for (int y = 0; y < 4; ++y) {
        int e = y * 16 + (lane & 15);
        int sg = wm + x * 16 + ((lane >> 4) << 2);
        f16x4 pk;
        pk[0] = (f16)acc[x][y][0]; pk[1] = (f16)acc[x][y][1];
        pk[2] = (f16)acc[x][y][2]; pk[3] = (f16)acc[x][y][3];
        *(f16x4*)&Ubuf[e * 130 + sg] = pk;
      }
    if (ki < 3) {  // prefetch next P (Psm safe to overwrite after sync above)
      int kn = k + 1;
#pragma unroll
      for (int v = 0; v < 2; ++v) {
        int flat = v * 256 + tid;
        int row = flat >> 3, cl = flat & 7, cg = cl ^ (row & 7);
        gl_lds16(phiT + (size_t)kn * 4096 + row * 64 + cg * 8,
                 &Psm[(v * 256 + wv * 64) * 8]);
      }
    }
    __syncthreads();  // Csm visible; P(kn) drained (implicit vmcnt(0))
    // stores to W3 quarter-chunk-major: per instr one chunk-col (wave-uniform
    // cc, lanes = consecutive e) -> 1 KB contiguous global stores.
    size_t obase = ((size_t)((b >> 1) * 24 + k) * 16 + st) * 16384 +
                   (size_t)(b & 1) * 512;
#pragma unroll
    for (int pass = 0; pass < 4; ++pass) {
      int g2 = pass * 256 + tid;
      int cc = g2 >> 6, e = g2 & 63;
      f16x8 val = *(const f16x8*)&Ubuf[e * 130 + cc * 8];
      *(f16x8*)&W3[obase + (size_t)cc * 1024 + e * 8] = val;
    }
  }
}

// ---- k_main: causal block-Toeplitz GEMM, 128x128 tiles, diag-major grid.
// R18: faithful T3+T4+T5 port. Ring of FOUR 8 KB quarter-slots (32 KB) +
// dbuf'd 5 KB D tables = 42 KB LDS -> 3 blocks/CU preserved (R16 lesson).
// Steady state: computing quarter g with quarters g+1..g+3 in flight ->
// counted vmcnt(6/7/8), never 0 until the tail (template depth-3 formula;
// R17's depth-1 was the documented coarse-split regression). Per phase:
// {2 gl_lds -> vmcnt(N) -> s_barrier -> 8 ds_read_b128 -> 16 MFMA
// (setprio) -> s_barrier}. W3 chunk-major layout makes the stage fully
// contiguous (perfect coalescing) AND the bf reads conflict-free
// (16 lanes read 256 B contiguous; no XOR — both-sides-or-neither).
__global__ __launch_bounds__(256, 3) void k_main(const f16* __restrict__ Dpre,
                                                 const f16* __restrict__ W3,
                                                 float* __restrict__ out) {
  __shared__ __align__(16) f16 Bq[4][4096];  // 4 ring slots x 8 KB
  __shared__ __align__(16) f16 Dsm[2][2560];
  int nt = blockIdx.x;
  int q = blockIdx.y;
  int diag = 0, off = 0;
  while (off + (16 - diag) <= q) { off += 16 - diag; ++diag; }
  int st = q - off;
  int mt = st + diag;
  int tid = threadIdx.x, lane = tid & 63, wv = tid >> 6;
  int wm = (wv & 1) * 64, wn = (wv >> 1) * 64;
  int ml = lane & 15, qv = lane >> 4;
  int p264 = (7 - (ml & 7)) * 264;           // phase row in Dsm
  int yb = (ml < 8 ? 120 : 112) - wm;        // y0 = s0 - x*16 + yb

  f32x4 zero = {0.f, 0.f, 0.f, 0.f};
  f32x4 acc[4][4];
#pragma unroll
  for (int x = 0; x < 4; ++x)
#pragma unroll
    for (int y = 0; y < 4; ++y) acc[x][y] = zero;

  const f16* dplane = Dpre + (size_t)(diag * 24) * 2560;
  const f16* base0 = W3 + (size_t)(nt * 384 + st) * 16384;  // (nt*24+0)*16+st

  // D table stage: 320 chunks (256 all-waves + 64 by wave 0). 1 op (w0: 2).
  auto stageD = [&](int buf, int kk) {
    const f16* dk = dplane + kk * 2560;
    gl_lds16(dk + (size_t)tid * 8, &Dsm[buf][wv * 512]);
    if (wv == 0) gl_lds16(dk + (size_t)(256 + lane) * 8, &Dsm[buf][2048]);
  };
  // Quarter stage: 8 KB contiguous from W3 -> linear LDS. 2 ops/wave.
  auto stageB = [&](int slot, int kk, int jj) {
    const f16* src = base0 + (size_t)kk * 262144 + jj * 4096;
    gl_lds16(src + (size_t)tid * 8, &Bq[slot][wv * 512]);
    gl_lds16(src + (size_t)(256 + tid) * 8, &Bq[slot][2048 + wv * 512]);
  };
  // One quarter: 8 ds_read_b128 + 16 MFMA (ks = quarter index within k).
  auto computeQ = [&](int ks, int slot, int dbuf) {
    int s0q = ks * 32 + qv * 8;
    f16x8 af[4], bf[4];
#pragma unroll
    for (int x = 0; x < 4; ++x)
      af[x] = *(const f16x8*)&Dsm[dbuf][p264 + s0q - x * 16 + yb];
#pragma unroll
    for (int y = 0; y < 4; ++y) {
      int n = wn + y * 16 + ml;
      bf[y] = *(const f16x8*)&Bq[slot][(qv * 128 + n) * 8];
    }
    __builtin_amdgcn_s_setprio(1);
#pragma unroll
    for (int x = 0; x < 4; ++x)
#pragma unroll
      for (int y = 0; y < 4; ++y)
        acc[x][y] = __builtin_amdgcn_mfma_f32_16x16x32_f16(af[x], bf[y], acc[x][y], 0, 0, 0);
    __builtin_amdgcn_s_setprio(0);
  };

  // prologue: D(0) + quarters 0,1,2 in flight (7 ops; w0: 8)
  stageD(0, 0);
  stageB(0, 0, 0);
  stageB(1, 0, 1);
  stageB(2, 0, 2);

  for (int k = 0; k < 24; ++k) {
    const int dbuf = k & 1;
#pragma unroll
    for (int j = 0; j < 4; ++j) {
      // issue stage for quarter g+3 (g = 4k+j; slot (j+3)&3)
      if (k < 23) {
        if (j == 0) {
          stageB(3, k, 3);
        } else {
          if (j == 1) stageD((k + 1) & 1, k + 1);
          stageB(j - 1, k + 1, j - 1);
        }
      } else if (j == 0) {
        stageB(3, 23, 3);
      }
      __builtin_amdgcn_sched_barrier(0);
      // counted wait for quarter g (in flight: g+1..g+3 = 6 B-ops, +1/+2 D)
      if (k < 23) {
        if (j == 0) asm volatile("s_waitcnt vmcnt(6)" ::: "memory");
        else if (wv == 0) asm volatile("s_waitcnt vmcnt(8)" ::: "memory");
        else asm volatile("s_waitcnt vmcnt(7)" ::: "memory");
      } else {
        if (j == 0) asm volatile("s_waitcnt vmcnt(6)" ::: "memory");
        else if (j == 1) asm volatile("s_waitcnt vmcnt(4)" ::: "memory");
        else if (j == 2) asm volatile("s_waitcnt vmcnt(2)" ::: "memory");
        else asm volatile("s_waitcnt vmcnt(0)" ::: "memory");
      }
      __builtin_amdgcn_s_barrier();  // quarter g visible to all waves
      __builtin_amdgcn_sched_barrier(0);
      computeQ(j, j, dbuf);  // slot g&3 == j
      __builtin_amdgcn_sched_barrier(0);
      __builtin_amdgcn_s_barrier();  // slot j free for overwrite next iter
      __builtin_amdgcn_sched_barrier(0);
    }
  }

  int t0 = mt * 128 + wm;
  int n0 = nt * 128 + wn;
#pragma unroll
  for (int x = 0; x < 4; ++x) {
    int rbase = t0 + x * 16 + (qv << 2);
#pragma unroll
    for (int y = 0; y < 4; ++y) {
      int col = n0 + y * 16 + ml;
      int b = col >> 6, e = col & 63;
#pragma unroll
      for (int r = 0; r < 4; ++r)
        atomicAdd(&out[((size_t)(b * 2048 + rbase + r)) * 64 + e], acc[x][y][r]);
    }
  }
}

extern "C" void kernel_launch(void* const* d_in, const int* in_sizes, int n_in,
                              void* d_out, int out_size, void* d_ws, size_t ws_size,
                              hipStream_t stream) {
  const float* inputs = (const float*)d_in[0];  // [16,2048,64]
  const float* m_phi = (const float*)d_in[1];   // [1536,64]
  const float* ev = (const float*)d_in[2];      // [24]
  const float* evec = (const float*)d_in[3];    // [2048,24]
  float* out = (float*)d_out;                   // [16,2048,64] fp32
  char* ws = (char*)d_ws;
  // ws layout: Dpre 1,966,080 | phiT 196,608 | uin 4,194,304 | W3 100,663,296
  f16* Dpre = (f16*)(ws);
  f16* phiT = (f16*)(ws + 1966080);
  f16* uin = (f16*)(ws + 2162688);
  f16* W3 = (f16*)(ws + 6356992);

  hipLaunchKernelGGL(k_pre0, dim3(728), dim3(256), 0, stream,
                     inputs, m_phi, ev, evec, phiT, uin, Dpre, out);
  hipLaunchKernelGGL(k_w, dim3(1536), dim3(256), 0, stream, uin, phiT, W3);
  hipLaunchKernelGGL(k_main, dim3(8, 136), dim3(256), 0, stream, Dpre, W3, out);
}